// Round 1
// baseline (681.416 us; speedup 1.0000x reference)
//
#include <hip/hip_runtime.h>
#include <cmath>

// node_learning: out = tanh((adj @ X) @ Wn^T + X @ Ws^T)
// Fold: (adj@X)@Wn^T == adj@(X@Wn^T).  Big GEMM done in bf16 hi/lo split
// (3 MFMA passes, error ~2^-17 rel) -> memory-bound at ~63us floor.

#define N_NODES 10000
#define EMB 128
#define XNT_STRIDE 10240   // padded row length (elems) of transposed Xn, 64B-aligned rows
#define KC 768             // K-chunk per block in main GEMM (24 sub-tiles of 32)
#define NKCH 14            // ceil(10000/768)
#define LDSW 40            // LDS row stride in bf16 (pad 32->40 for bank uniformity)

typedef __bf16 bf16x8 __attribute__((ext_vector_type(8)));
typedef float  f32x4  __attribute__((ext_vector_type(4)));

__device__ __forceinline__ bf16x8 bzero8() {
    bf16x8 v;
#pragma unroll
    for (int i = 0; i < 8; ++i) v[i] = (__bf16)0.0f;
    return v;
}

// ---------------------------------------------------------------------------
// prep: Xn = X @ Wn^T  (fp32), split to bf16 hi/lo, store transposed
// xnt[c][n], row stride XNT_STRIDE.
// ---------------------------------------------------------------------------
__global__ __launch_bounds__(256) void prep_kernel(
    const float* __restrict__ X, const float* __restrict__ Wn,
    __bf16* __restrict__ xnt_hi, __bf16* __restrict__ xnt_lo)
{
    __shared__ float Xl[32 * EMB];
    const int tid = threadIdx.x;
    const int n0 = blockIdx.x * 32;

#pragma unroll
    for (int i = 0; i < 4; ++i) {
        int idx = tid + i * 256;            // float4 index 0..1023
        int r = idx >> 5;
        int c4 = (idx & 31) << 2;
        int row = n0 + r;
        float4 v = make_float4(0.f, 0.f, 0.f, 0.f);
        if (row < N_NODES) v = *(const float4*)(X + (size_t)row * EMB + c4);
        *(float4*)(Xl + r * EMB + c4) = v;
    }
    __syncthreads();

    const int c = tid & 127;
    const int half = tid >> 7;
    const float* wrow = Wn + c * EMB;

    float acc[16];
#pragma unroll
    for (int r = 0; r < 16; ++r) acc[r] = 0.f;

    for (int k4 = 0; k4 < 32; ++k4) {
        float4 w = *(const float4*)(wrow + k4 * 4);
#pragma unroll
        for (int r = 0; r < 16; ++r) {
            float4 x = *(const float4*)(Xl + (half * 16 + r) * EMB + k4 * 4);
            acc[r] += x.x * w.x + x.y * w.y + x.z * w.z + x.w * w.w;
        }
    }

    size_t base = (size_t)c * XNT_STRIDE + n0 + half * 16;
#pragma unroll
    for (int r = 0; r < 16; ++r) {
        int row = n0 + half * 16 + r;
        if (row < N_NODES) {
            float f = acc[r];
            __bf16 h = (__bf16)f;
            __bf16 l = (__bf16)(f - (float)h);
            xnt_hi[base + r] = h;
            xnt_lo[base + r] = l;
        }
    }
}

// ---------------------------------------------------------------------------
// gemm: Y += adj[m0:m0+128, kc0:kc_end] @ Xn[kc0:kc_end, :]  via bf16 hi/lo
// MFMA (16x16x32), atomicAdd into Y (d_out, pre-zeroed).
// ---------------------------------------------------------------------------
__device__ __forceinline__ void g_load(
    const float* __restrict__ arow_p, bool arv,
    const __bf16* __restrict__ bh_p, const __bf16* __restrict__ bl_p,
    int k0, int kc_end, int akq, int bkq, float4 av[4], bf16x8 bv[4])
{
    int ak = k0 + akq * 16;
#pragma unroll
    for (int i = 0; i < 4; ++i) {
        float4 v = make_float4(0.f, 0.f, 0.f, 0.f);
        int k = ak + i * 4;
        if (arv && k < kc_end) v = *(const float4*)(arow_p + k);
        av[i] = v;
    }
    int bk = k0 + bkq * 16;
    if (bk < kc_end) {
        bv[0] = *(const bf16x8*)(bh_p + bk);
        bv[1] = *(const bf16x8*)(bh_p + bk + 8);
        bv[2] = *(const bf16x8*)(bl_p + bk);
        bv[3] = *(const bf16x8*)(bl_p + bk + 8);
    } else {
        bv[0] = bv[1] = bv[2] = bv[3] = bzero8();
    }
}

__global__ __launch_bounds__(256, 2) void gemm_kernel(
    const float* __restrict__ adj, const __bf16* __restrict__ xnt_hi,
    const __bf16* __restrict__ xnt_lo, float* __restrict__ Y)
{
    __shared__ __bf16 Ah[128 * LDSW];
    __shared__ __bf16 Al[128 * LDSW];
    __shared__ __bf16 Bh[128 * LDSW];
    __shared__ __bf16 Bl[128 * LDSW];

    const int tid = threadIdx.x;
    const int m0 = blockIdx.x * 128;
    const int kc0 = blockIdx.y * KC;
    const int kc_end = min(kc0 + KC, N_NODES);
    const int nsub = (kc_end - kc0 + 31) >> 5;

    const int lane = tid & 63;
    const int wave = tid >> 6;
    const int wm = (wave & 1) * 64;
    const int wn = (wave >> 1) * 64;
    const int fr = lane & 15;   // row/col within 16-tile
    const int q = lane >> 4;    // k-quad

    // staging assignment: 2 threads per row, 16-k halves
    const int am = tid >> 1, akq = tid & 1;
    const bool arv = (m0 + am) < N_NODES;
    const float* arow_p = adj + (size_t)(m0 + am) * N_NODES;
    const int bc = tid >> 1, bkq = tid & 1;
    const __bf16* bh_p = xnt_hi + (size_t)bc * XNT_STRIDE;
    const __bf16* bl_p = xnt_lo + (size_t)bc * XNT_STRIDE;

    f32x4 acc[4][4];
#pragma unroll
    for (int mt = 0; mt < 4; ++mt)
#pragma unroll
        for (int nt = 0; nt < 4; ++nt)
#pragma unroll
            for (int e = 0; e < 4; ++e) acc[mt][nt][e] = 0.f;

    float4 av[4];
    bf16x8 bv[4];
    g_load(arow_p, arv, bh_p, bl_p, kc0, kc_end, akq, bkq, av, bv);

    for (int ks = 0; ks < nsub; ++ks) {
        // convert A to hi/lo and store; store pre-split B
        bf16x8 ahv[2], alv[2];
#pragma unroll
        for (int i = 0; i < 16; ++i) {
            float f = ((const float*)av)[i];
            __bf16 h = (__bf16)f;
            __bf16 l = (__bf16)(f - (float)h);
            ahv[i >> 3][i & 7] = h;
            alv[i >> 3][i & 7] = l;
        }
        *(bf16x8*)&Ah[am * LDSW + akq * 16]     = ahv[0];
        *(bf16x8*)&Ah[am * LDSW + akq * 16 + 8] = ahv[1];
        *(bf16x8*)&Al[am * LDSW + akq * 16]     = alv[0];
        *(bf16x8*)&Al[am * LDSW + akq * 16 + 8] = alv[1];
        *(bf16x8*)&Bh[bc * LDSW + bkq * 16]     = bv[0];
        *(bf16x8*)&Bh[bc * LDSW + bkq * 16 + 8] = bv[1];
        *(bf16x8*)&Bl[bc * LDSW + bkq * 16]     = bv[2];
        *(bf16x8*)&Bl[bc * LDSW + bkq * 16 + 8] = bv[3];
        __syncthreads();

        // prefetch next tile's globals (overlaps MFMA phase; safe-zero past end)
        float4 av2[4];
        bf16x8 bv2[4];
        g_load(arow_p, arv, bh_p, bl_p, kc0 + (ks + 1) * 32, kc_end, akq, bkq, av2, bv2);

        bf16x8 a_h[4], a_l[4], b_h[4], b_l[4];
#pragma unroll
        for (int t = 0; t < 4; ++t) {
            a_h[t] = *(const bf16x8*)&Ah[(wm + t * 16 + fr) * LDSW + q * 8];
            a_l[t] = *(const bf16x8*)&Al[(wm + t * 16 + fr) * LDSW + q * 8];
            b_h[t] = *(const bf16x8*)&Bh[(wn + t * 16 + fr) * LDSW + q * 8];
            b_l[t] = *(const bf16x8*)&Bl[(wn + t * 16 + fr) * LDSW + q * 8];
        }
#pragma unroll
        for (int mt = 0; mt < 4; ++mt)
#pragma unroll
            for (int nt = 0; nt < 4; ++nt) {
                acc[mt][nt] = __builtin_amdgcn_mfma_f32_16x16x32_bf16(a_h[mt], b_h[nt], acc[mt][nt], 0, 0, 0);
                acc[mt][nt] = __builtin_amdgcn_mfma_f32_16x16x32_bf16(a_h[mt], b_l[nt], acc[mt][nt], 0, 0, 0);
                acc[mt][nt] = __builtin_amdgcn_mfma_f32_16x16x32_bf16(a_l[mt], b_h[nt], acc[mt][nt], 0, 0, 0);
            }
        __syncthreads();
#pragma unroll
        for (int i = 0; i < 4; ++i) { av[i] = av2[i]; bv[i] = bv2[i]; }
    }

    // C/D layout (verified m89): col = lane&15, row = (lane>>4)*4 + reg
#pragma unroll
    for (int mt = 0; mt < 4; ++mt) {
        int rbase = m0 + wm + mt * 16 + q * 4;
#pragma unroll
        for (int nt = 0; nt < 4; ++nt) {
            int col = wn + nt * 16 + fr;
#pragma unroll
            for (int r = 0; r < 4; ++r) {
                int row = rbase + r;
                if (row < N_NODES)
                    atomicAdd(Y + (size_t)row * EMB + col, acc[mt][nt][r]);
            }
        }
    }
}

// ---------------------------------------------------------------------------
// epi (fast path): out = tanh(out + X @ Ws^T), in place, 1 thread per elem set
// ---------------------------------------------------------------------------
__global__ __launch_bounds__(256) void epi_kernel(
    const float* __restrict__ X, const float* __restrict__ Wself,
    float* __restrict__ out)
{
    __shared__ float Xl[32 * EMB];
    const int tid = threadIdx.x;
    const int n0 = blockIdx.x * 32;

#pragma unroll
    for (int i = 0; i < 4; ++i) {
        int idx = tid + i * 256;
        int r = idx >> 5;
        int c4 = (idx & 31) << 2;
        int row = n0 + r;
        float4 v = make_float4(0.f, 0.f, 0.f, 0.f);
        if (row < N_NODES) v = *(const float4*)(X + (size_t)row * EMB + c4);
        *(float4*)(Xl + r * EMB + c4) = v;
    }
    __syncthreads();

    const int c = tid & 127;
    const int half = tid >> 7;
    const float* wrow = Wself + c * EMB;

    float acc[16];
#pragma unroll
    for (int r = 0; r < 16; ++r) acc[r] = 0.f;

    for (int k4 = 0; k4 < 32; ++k4) {
        float4 w = *(const float4*)(wrow + k4 * 4);
#pragma unroll
        for (int r = 0; r < 16; ++r) {
            float4 x = *(const float4*)(Xl + (half * 16 + r) * EMB + k4 * 4);
            acc[r] += x.x * w.x + x.y * w.y + x.z * w.z + x.w * w.w;
        }
    }

#pragma unroll
    for (int r = 0; r < 16; ++r) {
        int row = n0 + half * 16 + r;
        if (row < N_NODES) {
            size_t i = (size_t)row * EMB + c;
            out[i] = tanhf(out[i] + acc[r]);
        }
    }
}

// ---------------------------------------------------------------------------
// Fallback path (ws too small): fp32 VALU GEMM Y = adj@X atomically into out,
// then epi0 applies both weight matrices + tanh.
// ---------------------------------------------------------------------------
__global__ __launch_bounds__(256) void gemm0_kernel(
    const float* __restrict__ adj, const float* __restrict__ X,
    float* __restrict__ Y)
{
    __shared__ float As[128 * 33];
    __shared__ float Xs[32 * 132];
    const int tid = threadIdx.x;
    const int m0 = blockIdx.x * 128;
    const int kc0 = blockIdx.y * KC;
    const int kc_end = min(kc0 + KC, N_NODES);
    const int nsub = (kc_end - kc0 + 31) >> 5;

    const int am = tid >> 1, akq = tid & 1;
    const bool arv = (m0 + am) < N_NODES;
    const float* arow_p = adj + (size_t)(m0 + am) * N_NODES;
    const int xr = tid >> 3, xq = tid & 7;
    const int mq = tid >> 4, nq = tid & 15;

    float acc[8][8];
#pragma unroll
    for (int i = 0; i < 8; ++i)
#pragma unroll
        for (int j = 0; j < 8; ++j) acc[i][j] = 0.f;

    for (int ks = 0; ks < nsub; ++ks) {
        int k0 = kc0 + ks * 32;
#pragma unroll
        for (int i = 0; i < 4; ++i) {
            int k = k0 + akq * 16 + i * 4;
            float4 v = make_float4(0.f, 0.f, 0.f, 0.f);
            if (arv && k < kc_end) v = *(const float4*)(arow_p + k);
            float* d = As + am * 33 + akq * 16 + i * 4;
            d[0] = v.x; d[1] = v.y; d[2] = v.z; d[3] = v.w;
        }
#pragma unroll
        for (int i = 0; i < 4; ++i) {
            int c0 = xq * 16 + i * 4;
            int krow = k0 + xr;
            float4 v = make_float4(0.f, 0.f, 0.f, 0.f);
            if (krow < kc_end) v = *(const float4*)(X + (size_t)krow * EMB + c0);
            *(float4*)(Xs + xr * 132 + c0) = v;
        }
        __syncthreads();
        for (int k = 0; k < 32; ++k) {
            float a8[8];
#pragma unroll
            for (int i = 0; i < 8; ++i) a8[i] = As[(mq * 8 + i) * 33 + k];
            float4 x0 = *(const float4*)(Xs + k * 132 + nq * 8);
            float4 x1 = *(const float4*)(Xs + k * 132 + nq * 8 + 4);
            float x8[8] = { x0.x, x0.y, x0.z, x0.w, x1.x, x1.y, x1.z, x1.w };
#pragma unroll
            for (int i = 0; i < 8; ++i)
#pragma unroll
                for (int j = 0; j < 8; ++j) acc[i][j] += a8[i] * x8[j];
        }
        __syncthreads();
    }
#pragma unroll
    for (int i = 0; i < 8; ++i) {
        int row = m0 + mq * 8 + i;
        if (row < N_NODES) {
#pragma unroll
            for (int j = 0; j < 8; ++j)
                atomicAdd(Y + (size_t)row * EMB + nq * 8 + j, acc[i][j]);
        }
    }
}

__global__ __launch_bounds__(256) void epi0_kernel(
    const float* __restrict__ X, const float* __restrict__ Wn,
    const float* __restrict__ Ws, float* __restrict__ out)
{
    __shared__ float Xl[32 * EMB];
    __shared__ float Yl[32 * EMB];
    const int tid = threadIdx.x;
    const int n0 = blockIdx.x * 32;

#pragma unroll
    for (int i = 0; i < 4; ++i) {
        int idx = tid + i * 256;
        int r = idx >> 5;
        int c4 = (idx & 31) << 2;
        int row = n0 + r;
        float4 vx = make_float4(0.f, 0.f, 0.f, 0.f);
        float4 vy = vx;
        if (row < N_NODES) {
            vx = *(const float4*)(X + (size_t)row * EMB + c4);
            vy = *(const float4*)(out + (size_t)row * EMB + c4);
        }
        *(float4*)(Xl + r * EMB + c4) = vx;
        *(float4*)(Yl + r * EMB + c4) = vy;
    }
    __syncthreads();

    const int c = tid & 127;
    const int half = tid >> 7;
    const float* wn = Wn + c * EMB;
    const float* ws = Ws + c * EMB;

    float accn[16], accs[16];
#pragma unroll
    for (int r = 0; r < 16; ++r) { accn[r] = 0.f; accs[r] = 0.f; }

    for (int k4 = 0; k4 < 32; ++k4) {
        float4 a = *(const float4*)(wn + k4 * 4);
        float4 b = *(const float4*)(ws + k4 * 4);
#pragma unroll
        for (int r = 0; r < 16; ++r) {
            float4 y = *(const float4*)(Yl + (half * 16 + r) * EMB + k4 * 4);
            float4 x = *(const float4*)(Xl + (half * 16 + r) * EMB + k4 * 4);
            accn[r] += y.x * a.x + y.y * a.y + y.z * a.z + y.w * a.w;
            accs[r] += x.x * b.x + x.y * b.y + x.z * b.z + x.w * b.w;
        }
    }
#pragma unroll
    for (int r = 0; r < 16; ++r) {
        int row = n0 + half * 16 + r;
        if (row < N_NODES)
            out[(size_t)row * EMB + c] = tanhf(accn[r] + accs[r]);
    }
}

// ---------------------------------------------------------------------------
extern "C" void kernel_launch(void* const* d_in, const int* in_sizes, int n_in,
                              void* d_out, int out_size, void* d_ws, size_t ws_size,
                              hipStream_t stream) {
    const float* adj = (const float*)d_in[0];
    const float* X   = (const float*)d_in[1];
    const float* Wn  = (const float*)d_in[2];
    const float* Ws  = (const float*)d_in[3];
    float* out = (float*)d_out;

    const size_t xnt_elems = (size_t)EMB * XNT_STRIDE;
    const size_t need = xnt_elems * 2 * sizeof(unsigned short);

    hipMemsetAsync(d_out, 0, (size_t)N_NODES * EMB * sizeof(float), stream);

    if (ws_size >= need) {
        __bf16* xh = (__bf16*)d_ws;
        __bf16* xl = xh + xnt_elems;
        prep_kernel<<<(N_NODES + 31) / 32, 256, 0, stream>>>(X, Wn, xh, xl);
        gemm_kernel<<<dim3((N_NODES + 127) / 128, NKCH), 256, 0, stream>>>(adj, xh, xl, out);
        epi_kernel<<<(N_NODES + 31) / 32, 256, 0, stream>>>(X, Ws, out);
    } else {
        gemm0_kernel<<<dim3((N_NODES + 127) / 128, NKCH), 256, 0, stream>>>(adj, X, out);
        epi0_kernel<<<(N_NODES + 31) / 32, 256, 0, stream>>>(X, Wn, Ws, out);
    }
}

// Round 2
// 636.482 us; speedup vs baseline: 1.0706x; 1.0706x over previous
//
#include <hip/hip_runtime.h>
#include <cmath>

// node_learning: out = tanh((adj @ X) @ Wn^T + X @ Ws^T)
// Fold: (adj@X)@Wn^T == adj@(X@Wn^T).  Big GEMM in bf16 hi/lo split
// (3 MFMA passes, rel err ~2^-17) -> memory-bound, adj read floor ~63us.
// R2: atomics -> per-K-chunk partials in ws + fused reduction epilogue;
//     13 K-chunks (1027 blocks = 2.006 blocks/CU rounds); vectorized prep
//     stores; d_out memset removed.

#define N_NODES 10000
#define EMB 128
#define XNT_STRIDE 10240   // padded row length (elems) of transposed Xn
#define KC 800             // K-chunk per block in main GEMM (25 sub-tiles of 32)
#define NKCH 13            // ceil(10000/800)
#define LDSW 40            // LDS row stride in bf16 (pad 32->40, m97 lineage)

typedef __bf16 bf16x8 __attribute__((ext_vector_type(8)));
typedef float  f32x4  __attribute__((ext_vector_type(4)));

__device__ __forceinline__ bf16x8 bzero8() {
    bf16x8 v;
#pragma unroll
    for (int i = 0; i < 8; ++i) v[i] = (__bf16)0.0f;
    return v;
}

// ---------------------------------------------------------------------------
// prep: Xn = X @ Wn^T  (fp32), split to bf16 hi/lo, store transposed
// xnt[c][n], row stride XNT_STRIDE.  Vector 16B stores (10000 % 16 == 0).
// ---------------------------------------------------------------------------
__global__ __launch_bounds__(256) void prep_kernel(
    const float* __restrict__ X, const float* __restrict__ Wn,
    __bf16* __restrict__ xnt_hi, __bf16* __restrict__ xnt_lo)
{
    __shared__ float Xl[32 * EMB];
    const int tid = threadIdx.x;
    const int n0 = blockIdx.x * 32;

#pragma unroll
    for (int i = 0; i < 4; ++i) {
        int idx = tid + i * 256;            // float4 index 0..1023
        int r = idx >> 5;
        int c4 = (idx & 31) << 2;
        int row = n0 + r;
        float4 v = make_float4(0.f, 0.f, 0.f, 0.f);
        if (row < N_NODES) v = *(const float4*)(X + (size_t)row * EMB + c4);
        *(float4*)(Xl + r * EMB + c4) = v;
    }
    __syncthreads();

    const int c = tid & 127;
    const int half = tid >> 7;
    const float* wrow = Wn + c * EMB;

    float acc[16];
#pragma unroll
    for (int r = 0; r < 16; ++r) acc[r] = 0.f;

    for (int k4 = 0; k4 < 32; ++k4) {
        float4 w = *(const float4*)(wrow + k4 * 4);
#pragma unroll
        for (int r = 0; r < 16; ++r) {
            float4 x = *(const float4*)(Xl + (half * 16 + r) * EMB + k4 * 4);
            acc[r] += x.x * w.x + x.y * w.y + x.z * w.z + x.w * w.w;
        }
    }

    // rows n0+half*16 .. +15 are either all valid or all invalid (10000%16==0)
    if (n0 + half * 16 < N_NODES) {
        bf16x8 h0, h1, l0, l1;
#pragma unroll
        for (int r = 0; r < 16; ++r) {
            float f = acc[r];
            __bf16 h = (__bf16)f;
            __bf16 l = (__bf16)(f - (float)h);
            if (r < 8) { h0[r] = h; l0[r] = l; }
            else       { h1[r - 8] = h; l1[r - 8] = l; }
        }
        size_t base = (size_t)c * XNT_STRIDE + n0 + half * 16;
        *(bf16x8*)(xnt_hi + base)     = h0;
        *(bf16x8*)(xnt_hi + base + 8) = h1;
        *(bf16x8*)(xnt_lo + base)     = l0;
        *(bf16x8*)(xnt_lo + base + 8) = l1;
    }
}

// ---------------------------------------------------------------------------
// gemm: P[kc] = adj[m0:m0+128, kc0:kc_end] @ Xn[kc0:kc_end, :]  via bf16
// hi/lo MFMA (16x16x32); plain coalesced stores into per-chunk partial buf.
// ---------------------------------------------------------------------------
__device__ __forceinline__ void g_load(
    const float* __restrict__ arow_p, bool arv,
    const __bf16* __restrict__ bh_p, const __bf16* __restrict__ bl_p,
    int k0, int kc_end, int akq, int bkq, float4 av[4], bf16x8 bv[4])
{
    int ak = k0 + akq * 16;
#pragma unroll
    for (int i = 0; i < 4; ++i) {
        float4 v = make_float4(0.f, 0.f, 0.f, 0.f);
        int k = ak + i * 4;
        if (arv && k < kc_end) v = *(const float4*)(arow_p + k);
        av[i] = v;
    }
    int bk = k0 + bkq * 16;
    if (bk < kc_end) {
        bv[0] = *(const bf16x8*)(bh_p + bk);
        bv[1] = *(const bf16x8*)(bh_p + bk + 8);
        bv[2] = *(const bf16x8*)(bl_p + bk);
        bv[3] = *(const bf16x8*)(bl_p + bk + 8);
    } else {
        bv[0] = bv[1] = bv[2] = bv[3] = bzero8();
    }
}

__global__ __launch_bounds__(256, 2) void gemm_kernel(
    const float* __restrict__ adj, const __bf16* __restrict__ xnt_hi,
    const __bf16* __restrict__ xnt_lo, float* __restrict__ Ppart)
{
    __shared__ __bf16 Ah[128 * LDSW];
    __shared__ __bf16 Al[128 * LDSW];
    __shared__ __bf16 Bh[128 * LDSW];
    __shared__ __bf16 Bl[128 * LDSW];

    const int tid = threadIdx.x;
    const int m0 = blockIdx.x * 128;
    const int kc0 = blockIdx.y * KC;
    const int kc_end = min(kc0 + KC, N_NODES);
    const int nsub = (kc_end - kc0 + 31) >> 5;

    const int lane = tid & 63;
    const int wave = tid >> 6;
    const int wm = (wave & 1) * 64;
    const int wn = (wave >> 1) * 64;
    const int fr = lane & 15;   // row/col within 16-tile
    const int q = lane >> 4;    // k-quad

    // staging assignment: 2 threads per row, 16-k halves
    const int am = tid >> 1, akq = tid & 1;
    const bool arv = (m0 + am) < N_NODES;
    const float* arow_p = adj + (size_t)(m0 + am) * N_NODES;
    const int bc = tid >> 1, bkq = tid & 1;
    const __bf16* bh_p = xnt_hi + (size_t)bc * XNT_STRIDE;
    const __bf16* bl_p = xnt_lo + (size_t)bc * XNT_STRIDE;

    f32x4 acc[4][4];
#pragma unroll
    for (int mt = 0; mt < 4; ++mt)
#pragma unroll
        for (int nt = 0; nt < 4; ++nt)
#pragma unroll
            for (int e = 0; e < 4; ++e) acc[mt][nt][e] = 0.f;

    float4 av[4];
    bf16x8 bv[4];
    g_load(arow_p, arv, bh_p, bl_p, kc0, kc_end, akq, bkq, av, bv);

    for (int ks = 0; ks < nsub; ++ks) {
        // convert A to hi/lo and store; store pre-split B
        bf16x8 ahv[2], alv[2];
#pragma unroll
        for (int i = 0; i < 16; ++i) {
            float f = ((const float*)av)[i];
            __bf16 h = (__bf16)f;
            __bf16 l = (__bf16)(f - (float)h);
            ahv[i >> 3][i & 7] = h;
            alv[i >> 3][i & 7] = l;
        }
        *(bf16x8*)&Ah[am * LDSW + akq * 16]     = ahv[0];
        *(bf16x8*)&Ah[am * LDSW + akq * 16 + 8] = ahv[1];
        *(bf16x8*)&Al[am * LDSW + akq * 16]     = alv[0];
        *(bf16x8*)&Al[am * LDSW + akq * 16 + 8] = alv[1];
        *(bf16x8*)&Bh[bc * LDSW + bkq * 16]     = bv[0];
        *(bf16x8*)&Bh[bc * LDSW + bkq * 16 + 8] = bv[1];
        *(bf16x8*)&Bl[bc * LDSW + bkq * 16]     = bv[2];
        *(bf16x8*)&Bl[bc * LDSW + bkq * 16 + 8] = bv[3];
        __syncthreads();

        // prefetch next tile's globals (overlaps MFMA phase; safe-zero past end)
        float4 av2[4];
        bf16x8 bv2[4];
        g_load(arow_p, arv, bh_p, bl_p, kc0 + (ks + 1) * 32, kc_end, akq, bkq, av2, bv2);

        bf16x8 a_h[4], a_l[4], b_h[4], b_l[4];
#pragma unroll
        for (int t = 0; t < 4; ++t) {
            a_h[t] = *(const bf16x8*)&Ah[(wm + t * 16 + fr) * LDSW + q * 8];
            a_l[t] = *(const bf16x8*)&Al[(wm + t * 16 + fr) * LDSW + q * 8];
            b_h[t] = *(const bf16x8*)&Bh[(wn + t * 16 + fr) * LDSW + q * 8];
            b_l[t] = *(const bf16x8*)&Bl[(wn + t * 16 + fr) * LDSW + q * 8];
        }
#pragma unroll
        for (int mt = 0; mt < 4; ++mt)
#pragma unroll
            for (int nt = 0; nt < 4; ++nt) {
                acc[mt][nt] = __builtin_amdgcn_mfma_f32_16x16x32_bf16(a_h[mt], b_h[nt], acc[mt][nt], 0, 0, 0);
                acc[mt][nt] = __builtin_amdgcn_mfma_f32_16x16x32_bf16(a_h[mt], b_l[nt], acc[mt][nt], 0, 0, 0);
                acc[mt][nt] = __builtin_amdgcn_mfma_f32_16x16x32_bf16(a_l[mt], b_h[nt], acc[mt][nt], 0, 0, 0);
            }
        __syncthreads();
#pragma unroll
        for (int i = 0; i < 4; ++i) { av[i] = av2[i]; bv[i] = bv2[i]; }
    }

    // C/D layout (verified m89): col = lane&15, row = (lane>>4)*4 + reg
    float* P = Ppart + (size_t)blockIdx.y * ((size_t)N_NODES * EMB);
#pragma unroll
    for (int mt = 0; mt < 4; ++mt) {
        int rbase = m0 + wm + mt * 16 + q * 4;
#pragma unroll
        for (int nt = 0; nt < 4; ++nt) {
            int col = wn + nt * 16 + fr;
#pragma unroll
            for (int r = 0; r < 4; ++r) {
                int row = rbase + r;
                if (row < N_NODES)
                    P[(size_t)row * EMB + col] = acc[mt][nt][r];
            }
        }
    }
}

// ---------------------------------------------------------------------------
// epi (fast path): out = tanh(sum_p P[p] + X @ Ws^T)
// ---------------------------------------------------------------------------
__global__ __launch_bounds__(256) void epi_kernel(
    const float* __restrict__ X, const float* __restrict__ Wself,
    const float* __restrict__ Ppart, float* __restrict__ out)
{
    __shared__ float Xl[32 * EMB];
    const int tid = threadIdx.x;
    const int n0 = blockIdx.x * 32;

#pragma unroll
    for (int i = 0; i < 4; ++i) {
        int idx = tid + i * 256;
        int r = idx >> 5;
        int c4 = (idx & 31) << 2;
        int row = n0 + r;
        float4 v = make_float4(0.f, 0.f, 0.f, 0.f);
        if (row < N_NODES) v = *(const float4*)(X + (size_t)row * EMB + c4);
        *(float4*)(Xl + r * EMB + c4) = v;
    }
    __syncthreads();

    const int c = tid & 127;
    const int half = tid >> 7;
    const float* wrow = Wself + c * EMB;

    float acc[16];
#pragma unroll
    for (int r = 0; r < 16; ++r) acc[r] = 0.f;

    for (int k4 = 0; k4 < 32; ++k4) {
        float4 w = *(const float4*)(wrow + k4 * 4);
#pragma unroll
        for (int r = 0; r < 16; ++r) {
            float4 x = *(const float4*)(Xl + (half * 16 + r) * EMB + k4 * 4);
            acc[r] += x.x * w.x + x.y * w.y + x.z * w.z + x.w * w.w;
        }
    }

    if (n0 + half * 16 < N_NODES) {   // whole 16-row group valid (10000%16==0)
        const size_t rb = (size_t)(n0 + half * 16) * EMB + c;
        // reduce the 13 K-chunk partials (coalesced: lanes span c)
#pragma unroll
        for (int p = 0; p < NKCH; ++p) {
            const float* Pp = Ppart + (size_t)p * ((size_t)N_NODES * EMB) + rb;
#pragma unroll
            for (int r = 0; r < 16; ++r)
                acc[r] += Pp[(size_t)r * EMB];
        }
#pragma unroll
        for (int r = 0; r < 16; ++r)
            out[rb + (size_t)r * EMB] = tanhf(acc[r]);
    }
}

// ---------------------------------------------------------------------------
// Fallback path (ws too small): fp32 VALU GEMM Y = adj@X atomically into out,
// then epi0 applies both weight matrices + tanh.
// ---------------------------------------------------------------------------
__global__ __launch_bounds__(256) void gemm0_kernel(
    const float* __restrict__ adj, const float* __restrict__ X,
    float* __restrict__ Y)
{
    __shared__ float As[128 * 33];
    __shared__ float Xs[32 * 132];
    const int tid = threadIdx.x;
    const int m0 = blockIdx.x * 128;
    const int kc0 = blockIdx.y * KC;
    const int kc_end = min(kc0 + KC, N_NODES);
    const int nsub = (kc_end - kc0 + 31) >> 5;

    const int am = tid >> 1, akq = tid & 1;
    const bool arv = (m0 + am) < N_NODES;
    const float* arow_p = adj + (size_t)(m0 + am) * N_NODES;
    const int xr = tid >> 3, xq = tid & 7;
    const int mq = tid >> 4, nq = tid & 15;

    float acc[8][8];
#pragma unroll
    for (int i = 0; i < 8; ++i)
#pragma unroll
        for (int j = 0; j < 8; ++j) acc[i][j] = 0.f;

    for (int ks = 0; ks < nsub; ++ks) {
        int k0 = kc0 + ks * 32;
#pragma unroll
        for (int i = 0; i < 4; ++i) {
            int k = k0 + akq * 16 + i * 4;
            float4 v = make_float4(0.f, 0.f, 0.f, 0.f);
            if (arv && k < kc_end) v = *(const float4*)(arow_p + k);
            float* d = As + am * 33 + akq * 16 + i * 4;
            d[0] = v.x; d[1] = v.y; d[2] = v.z; d[3] = v.w;
        }
#pragma unroll
        for (int i = 0; i < 4; ++i) {
            int c0 = xq * 16 + i * 4;
            int krow = k0 + xr;
            float4 v = make_float4(0.f, 0.f, 0.f, 0.f);
            if (krow < kc_end) v = *(const float4*)(X + (size_t)krow * EMB + c0);
            *(float4*)(Xs + xr * 132 + c0) = v;
        }
        __syncthreads();
        for (int k = 0; k < 32; ++k) {
            float a8[8];
#pragma unroll
            for (int i = 0; i < 8; ++i) a8[i] = As[(mq * 8 + i) * 33 + k];
            float4 x0 = *(const float4*)(Xs + k * 132 + nq * 8);
            float4 x1 = *(const float4*)(Xs + k * 132 + nq * 8 + 4);
            float x8[8] = { x0.x, x0.y, x0.z, x0.w, x1.x, x1.y, x1.z, x1.w };
#pragma unroll
            for (int i = 0; i < 8; ++i)
#pragma unroll
                for (int j = 0; j < 8; ++j) acc[i][j] += a8[i] * x8[j];
        }
        __syncthreads();
    }
#pragma unroll
    for (int i = 0; i < 8; ++i) {
        int row = m0 + mq * 8 + i;
        if (row < N_NODES) {
#pragma unroll
            for (int j = 0; j < 8; ++j)
                atomicAdd(Y + (size_t)row * EMB + nq * 8 + j, acc[i][j]);
        }
    }
}

__global__ __launch_bounds__(256) void epi0_kernel(
    const float* __restrict__ X, const float* __restrict__ Wn,
    const float* __restrict__ Ws, float* __restrict__ out)
{
    __shared__ float Xl[32 * EMB];
    __shared__ float Yl[32 * EMB];
    const int tid = threadIdx.x;
    const int n0 = blockIdx.x * 32;

#pragma unroll
    for (int i = 0; i < 4; ++i) {
        int idx = tid + i * 256;
        int r = idx >> 5;
        int c4 = (idx & 31) << 2;
        int row = n0 + r;
        float4 vx = make_float4(0.f, 0.f, 0.f, 0.f);
        float4 vy = vx;
        if (row < N_NODES) {
            vx = *(const float4*)(X + (size_t)row * EMB + c4);
            vy = *(const float4*)(out + (size_t)row * EMB + c4);
        }
        *(float4*)(Xl + r * EMB + c4) = vx;
        *(float4*)(Yl + r * EMB + c4) = vy;
    }
    __syncthreads();

    const int c = tid & 127;
    const int half = tid >> 7;
    const float* wn = Wn + c * EMB;
    const float* ws = Ws + c * EMB;

    float accn[16], accs[16];
#pragma unroll
    for (int r = 0; r < 16; ++r) { accn[r] = 0.f; accs[r] = 0.f; }

    for (int k4 = 0; k4 < 32; ++k4) {
        float4 a = *(const float4*)(wn + k4 * 4);
        float4 b = *(const float4*)(ws + k4 * 4);
#pragma unroll
        for (int r = 0; r < 16; ++r) {
            float4 y = *(const float4*)(Yl + (half * 16 + r) * EMB + k4 * 4);
            float4 x = *(const float4*)(Xl + (half * 16 + r) * EMB + k4 * 4);
            accn[r] += y.x * a.x + y.y * a.y + y.z * a.z + y.w * a.w;
            accs[r] += x.x * b.x + x.y * b.y + x.z * b.z + x.w * b.w;
        }
    }
#pragma unroll
    for (int r = 0; r < 16; ++r) {
        int row = n0 + half * 16 + r;
        if (row < N_NODES)
            out[(size_t)row * EMB + c] = tanhf(accn[r] + accs[r]);
    }
}

// ---------------------------------------------------------------------------
extern "C" void kernel_launch(void* const* d_in, const int* in_sizes, int n_in,
                              void* d_out, int out_size, void* d_ws, size_t ws_size,
                              hipStream_t stream) {
    const float* adj = (const float*)d_in[0];
    const float* X   = (const float*)d_in[1];
    const float* Wn  = (const float*)d_in[2];
    const float* Ws  = (const float*)d_in[3];
    float* out = (float*)d_out;

    const size_t xnt_elems = (size_t)EMB * XNT_STRIDE;
    const size_t xnt_bytes = xnt_elems * 2 * sizeof(unsigned short);   // hi+lo
    const size_t part_bytes = (size_t)NKCH * N_NODES * EMB * sizeof(float);

    if (ws_size >= xnt_bytes + part_bytes) {
        // fast path: partials in ws, no atomics, no d_out memset
        __bf16* xh = (__bf16*)d_ws;
        __bf16* xl = xh + xnt_elems;
        float* Ppart = (float*)((char*)d_ws + xnt_bytes);
        prep_kernel<<<(N_NODES + 31) / 32, 256, 0, stream>>>(X, Wn, xh, xl);
        gemm_kernel<<<dim3((N_NODES + 127) / 128, NKCH), 256, 0, stream>>>(adj, xh, xl, Ppart);
        epi_kernel<<<(N_NODES + 31) / 32, 256, 0, stream>>>(X, Ws, Ppart, out);
    } else {
        // fallback: fp32 VALU GEMM with atomics into pre-zeroed out
        hipMemsetAsync(d_out, 0, (size_t)N_NODES * EMB * sizeof(float), stream);
        gemm0_kernel<<<dim3((N_NODES + 127) / 128, NKCH), 256, 0, stream>>>(adj, X, out);
        epi0_kernel<<<(N_NODES + 31) / 32, 256, 0, stream>>>(X, Wn, Ws, out);
    }
}